// Round 4
// baseline (590.110 us; speedup 1.0000x reference)
//
#include <hip/hip_runtime.h>
#include <math.h>

#define B_ 16
#define S_ 1024
#define D_ 256
#define F_ 256
#define T_ 8192
#define ROWS (B_ * S_)  // 16384

typedef __attribute__((ext_vector_type(8))) short short8x;
typedef __attribute__((ext_vector_type(4))) float f32x4;

static __device__ __forceinline__ unsigned short f2bf(float f) {
    unsigned u = __float_as_uint(f);
    unsigned r = (u + 0x7FFFu + ((u >> 16) & 1u)) >> 16;  // round-to-nearest-even
    return (unsigned short)r;
}

// ============================================================
// K1: z=0: x' = x + note_pitch @ np_w + np_b  (BM=64 BN=64, 4x4/thread)
//     z=1: bf16 weight prep wt[t][k][o][c] (t in {pp1,ep1,pp2,ep2}) + red init
// grid (256, 4, 2)
// ============================================================
__global__ __launch_bounds__(256) void noteproj_kernel(
    const float* __restrict__ x, const float* __restrict__ note,
    const float* __restrict__ w, const float* __restrict__ bias,
    float* __restrict__ xp, unsigned* __restrict__ red,
    const float* __restrict__ pw1, const float* __restrict__ ew1,
    const float* __restrict__ pw2, const float* __restrict__ ew2,
    unsigned short* __restrict__ wt)
{
    if (blockIdx.z == 1) {
        int flat = blockIdx.y * 256 + blockIdx.x;           // 0..1023
        if (flat == 0 && threadIdx.x == 0) {
            red[0] = 0u;            // max ||xn||
            red[1] = 0x7F7FFFFFu;   // min ||x'||
            red[2] = 0u;            // max ||x'||
        }
        int idx = flat * 256 + threadIdx.x;                 // 0..262143
        int t = idx >> 16;
        int rem = idx & 65535;
        int o = rem >> 8, c = rem & 255;
        const float* src = (t == 0) ? pw1 : (t == 1) ? ew1 : (t == 2) ? pw2 : ew2;
        const float* p = src + ((size_t)o * 256 + c) * 3;
        unsigned short* dst = wt + (size_t)t * 196608;
        #pragma unroll
        for (int k = 0; k < 3; ++k)
            dst[((size_t)k * 256 + o) * 256 + c] = f2bf(p[k]);
        return;
    }
    __shared__ float As[16][66];
    __shared__ float Bs[16][68];
    const int tid = threadIdx.x;
    const int m0 = blockIdx.x << 6;
    const int o0 = blockIdx.y << 6;
    const int tc = tid & 15, tr = tid >> 4;
    const int r = tr << 2, oc = tc << 2;
    const int tA = tid >> 2, cg = (tid & 3) << 2;
    const int cB = tid >> 4, oB = (tid & 15) << 2;
    float acc[4][4] = {};

    for (int c0 = 0; c0 < D_; c0 += 16) {
        float4 av = *(const float4*)(note + (size_t)(m0 + tA) * D_ + c0 + cg);
        As[cg + 0][tA] = av.x; As[cg + 1][tA] = av.y;
        As[cg + 2][tA] = av.z; As[cg + 3][tA] = av.w;
        *(float4*)&Bs[cB][oB] = *(const float4*)(w + (size_t)(c0 + cB) * D_ + o0 + oB);
        __syncthreads();
        #pragma unroll
        for (int c = 0; c < 16; ++c) {
            float a[4], bv[4];
            #pragma unroll
            for (int m = 0; m < 4; ++m) a[m] = As[c][r + m];
            #pragma unroll
            for (int j = 0; j < 4; ++j) bv[j] = Bs[c][oc + j];
            #pragma unroll
            for (int i = 0; i < 4; ++i)
                #pragma unroll
                for (int j = 0; j < 4; ++j)
                    acc[i][j] = fmaf(a[i], bv[j], acc[i][j]);
        }
        __syncthreads();
    }
    #pragma unroll
    for (int i = 0; i < 4; ++i) {
        size_t row = (size_t)(m0 + r + i);
        const float* xr = x + row * D_ + o0 + oc;
        float4 v;
        v.x = acc[i][0] + bias[o0 + oc + 0] + xr[0];
        v.y = acc[i][1] + bias[o0 + oc + 1] + xr[1];
        v.z = acc[i][2] + bias[o0 + oc + 2] + xr[2];
        v.w = acc[i][3] + bias[o0 + oc + 3] + xr[3];
        *(float4*)(xp + row * D_ + o0 + oc) = v;
    }
}

// ============================================================
// K2: layernorm + norms + bf16 copy of x'. 1 wave = 1 row.
// ============================================================
__global__ __launch_bounds__(256) void rowstats_kernel(
    const float* __restrict__ xp, const float* __restrict__ g, const float* __restrict__ bb,
    float* __restrict__ xn, float* __restrict__ nxn, float* __restrict__ nx,
    unsigned short* __restrict__ xpb)
{
    int row = blockIdx.x * 4 + (threadIdx.x >> 6);
    int lane = threadIdx.x & 63;
    float4 v = ((const float4*)(xp + (size_t)row * D_))[lane];
    ushort4 bv4;
    bv4.x = f2bf(v.x); bv4.y = f2bf(v.y); bv4.z = f2bf(v.z); bv4.w = f2bf(v.w);
    ((ushort4*)xpb)[(size_t)row * 64 + lane] = bv4;

    float s = v.x + v.y + v.z + v.w;
    float sq = v.x * v.x + v.y * v.y + v.z * v.z + v.w * v.w;
    #pragma unroll
    for (int m = 32; m; m >>= 1) { s += __shfl_xor(s, m); sq += __shfl_xor(sq, m); }
    float mean = s * (1.f / 256.f);
    float var = sq * (1.f / 256.f) - mean * mean;
    float rs = rsqrtf(var + 1e-5f);
    float4 gv = ((const float4*)g)[lane];
    float4 bv = ((const float4*)bb)[lane];
    float4 o;
    o.x = gv.x * (v.x - mean) * rs + bv.x;
    o.y = gv.y * (v.y - mean) * rs + bv.y;
    o.z = gv.z * (v.z - mean) * rs + bv.z;
    o.w = gv.w * (v.w - mean) * rs + bv.w;
    ((float4*)(xn + (size_t)row * D_))[lane] = o;
    float q = o.x * o.x + o.y * o.y + o.z * o.z + o.w * o.w;
    #pragma unroll
    for (int m = 32; m; m >>= 1) q += __shfl_xor(q, m);
    if (lane == 0) { nxn[row] = sqrtf(q); nx[row] = sqrtf(sq); }
}

// ============================================================
// K3: global reduce via uint-monotonic atomics (positive floats)
// ============================================================
__global__ __launch_bounds__(256) void reduce_fast_kernel(
    const float* __restrict__ nxn, const float* __restrict__ nx, unsigned* __restrict__ red)
{
    int tid = threadIdx.x;
    int lane = tid & 63, wave = tid >> 6;
    float mxn = 0.f, mnx = 3.0e38f, mxx = 0.f;
    for (int i = blockIdx.x * 256 + tid; i < ROWS; i += 32 * 256) {
        mxn = fmaxf(mxn, nxn[i]);
        float v = nx[i];
        mnx = fminf(mnx, v);
        mxx = fmaxf(mxx, v);
    }
    #pragma unroll
    for (int m = 32; m; m >>= 1) {
        mxn = fmaxf(mxn, __shfl_xor(mxn, m));
        mnx = fminf(mnx, __shfl_xor(mnx, m));
        mxx = fmaxf(mxx, __shfl_xor(mxx, m));
    }
    __shared__ float a0[4], a1[4], a2[4];
    if (lane == 0) { a0[wave] = mxn; a1[wave] = mnx; a2[wave] = mxx; }
    __syncthreads();
    if (tid == 0) {
        #pragma unroll
        for (int w2 = 1; w2 < 4; ++w2) {
            mxn = fmaxf(mxn, a0[w2]); mnx = fminf(mnx, a1[w2]); mxx = fmaxf(mxx, a2[w2]);
        }
        atomicMax(&red[0], __float_as_uint(mxn));
        atomicMin(&red[1], __float_as_uint(mnx));
        atomicMax(&red[2], __float_as_uint(mxx));
    }
}

// ============================================================
// K4: mixed conv stage, BM=64 everywhere.
//   z=0: dp fp32 (1024 blocks, 4x4/thread, reg prefetch)
//   z=1,2: pp/ep bf16 MFMA (2048 light blocks, swizzled B tile)
// grid (256, 4, 3)
// ============================================================
struct ConvMix {
    const float* in0; const float* w0; const float* b0; float* out0;   // dp fp32
    const unsigned short* inb[2];     // bf16 inputs [B*S][256]
    const unsigned short* wt[2];      // bf16 weights [3][256][256]
    const float* bias[2];
    void* out[2];
    int bfout;                        // 1: write bf16, 0: write fp32
};

__global__ __launch_bounds__(256, 6) void convmix_kernel(ConvMix cb)
{
    __shared__ __align__(16) char smem[17664];
    const int tid = threadIdx.x;
    const int z = blockIdx.z;
    const int b = blockIdx.x >> 4;
    const int s0 = (blockIdx.x & 15) << 6;
    const int o0 = blockIdx.y << 6;

    if (z == 0) {
        // ---------------- fp32 dp path, BM=64 ----------------
        float* AsF = (float*)smem;            // [16][68]  (t dim 0..65)
        float* BsF = (float*)(smem + 4352);   // [3][16][68]
        const int tc = tid & 15, tr = tid >> 4;
        const int r = tr << 2, oc = tc << 2;
        const int oB = tid >> 2;
        const int qB = (tid & 3) * 12;
        const int rowA0 = tid >> 2, cgA0 = (tid & 3) << 2;   // slot tid
        const int rowA1 = 64 + (tid >> 2);                   // slot tid+256 (tid<8)
        const float* inb = cb.in0 + (size_t)b * S_ * D_;
        float acc[4][4] = {};
        float4 pa0, pa1; float pb[12];

        auto pref = [&](int c0) {
            {
                int s = s0 - 1 + rowA0;
                float4 v = make_float4(0.f, 0.f, 0.f, 0.f);
                if (s >= 0 && s < S_) v = *(const float4*)(inb + (size_t)s * D_ + c0 + cgA0);
                pa0 = v;
            }
            if (tid < 8) {
                int s = s0 - 1 + rowA1;
                float4 v = make_float4(0.f, 0.f, 0.f, 0.f);
                if (s >= 0 && s < S_) v = *(const float4*)(inb + (size_t)s * D_ + c0 + cgA0);
                pa1 = v;
            }
            const float* wp = cb.w0 + ((size_t)(o0 + oB) * D_ + c0) * 3 + qB;
            #pragma unroll
            for (int j = 0; j < 12; ++j) pb[j] = wp[j];
        };
        pref(0);
        for (int c0 = 0; c0 < D_; c0 += 16) {
            AsF[(cgA0 + 0) * 68 + rowA0] = pa0.x;
            AsF[(cgA0 + 1) * 68 + rowA0] = pa0.y;
            AsF[(cgA0 + 2) * 68 + rowA0] = pa0.z;
            AsF[(cgA0 + 3) * 68 + rowA0] = pa0.w;
            if (tid < 8) {
                AsF[(cgA0 + 0) * 68 + rowA1] = pa1.x;
                AsF[(cgA0 + 1) * 68 + rowA1] = pa1.y;
                AsF[(cgA0 + 2) * 68 + rowA1] = pa1.z;
                AsF[(cgA0 + 3) * 68 + rowA1] = pa1.w;
            }
            #pragma unroll
            for (int j = 0; j < 12; ++j) {
                int m = qB + j;
                BsF[((m % 3) * 16 + (m / 3)) * 68 + oB] = pb[j];
            }
            __syncthreads();
            if (c0 + 16 < D_) pref(c0 + 16);
            #pragma unroll
            for (int c = 0; c < 16; ++c) {
                float a[6];
                #pragma unroll
                for (int m = 0; m < 6; ++m) a[m] = AsF[c * 68 + r + m];
                #pragma unroll
                for (int k = 0; k < 3; ++k) {
                    float4 bv = *(const float4*)&BsF[(k * 16 + c) * 68 + oc];
                    #pragma unroll
                    for (int i = 0; i < 4; ++i) {
                        float av = a[i + k];
                        acc[i][0] = fmaf(av, bv.x, acc[i][0]);
                        acc[i][1] = fmaf(av, bv.y, acc[i][1]);
                        acc[i][2] = fmaf(av, bv.z, acc[i][2]);
                        acc[i][3] = fmaf(av, bv.w, acc[i][3]);
                    }
                }
            }
            __syncthreads();
        }
        float bj0 = cb.b0[o0 + oc + 0], bj1 = cb.b0[o0 + oc + 1];
        float bj2 = cb.b0[o0 + oc + 2], bj3 = cb.b0[o0 + oc + 3];
        float* outb = cb.out0 + (size_t)b * S_ * D_;
        #pragma unroll
        for (int i = 0; i < 4; ++i) {
            int s = s0 + r + i;
            float4 v;
            v.x = fmaxf(acc[i][0] + bj0, 0.f);
            v.y = fmaxf(acc[i][1] + bj1, 0.f);
            v.z = fmaxf(acc[i][2] + bj2, 0.f);
            v.w = fmaxf(acc[i][3] + bj3, 0.f);
            *(float4*)(outb + (size_t)s * D_ + o0 + oc) = v;
        }
    } else {
        // ---------------- bf16 MFMA path (pp/ep), BM=64 ----------------
        const int z1 = z - 1;
        unsigned short* Asb = (unsigned short*)smem;            // [66][40]
        unsigned short* Bsb = (unsigned short*)(smem + 5280);   // [3][4][4][16][8] = 6144 shorts
        const unsigned short* inb = cb.inb[z1] + (size_t)b * S_ * D_;
        const unsigned short* wtp = cb.wt[z1];
        const float* bias = cb.bias[z1];
        const int wave = tid >> 6, lane = tid & 63;
        const int wm = wave << 4;              // 16 rows per wave
        const int lm = lane & 15, hk = lane >> 4, lk8 = hk << 3;
        f32x4 acc[4] = {};

        // A staging: 66 rows x 4 chunks = 264 slots
        const int taA0 = tid >> 2, chA = (tid & 3) << 3;      // slot tid
        const int taA1 = 64 + (tid >> 2);                     // slot tid+256 (tid<8)
        // B staging: 768 slots, swizzled dest [k][nt][h][lm]
        int kb[3], obv[3], hB[3], dstB[3];
        #pragma unroll
        for (int rr = 0; rr < 3; ++rr) {
            int slotB = tid + (rr << 8);
            kb[rr] = slotB >> 8;
            int rem = slotB & 255;
            obv[rr] = rem >> 2;
            hB[rr] = rem & 3;
            dstB[rr] = (kb[rr] * 4 + (obv[rr] >> 4)) * 512 + hB[rr] * 128 + (obv[rr] & 15) * 8;
        }
        uint4 pa0, pa1, pb[3];
        auto pref = [&](int c0) {
            {
                int s = s0 - 1 + taA0;
                uint4 v = make_uint4(0u, 0u, 0u, 0u);
                if (s >= 0 && s < S_) v = *(const uint4*)(const void*)(inb + (size_t)s * D_ + c0 + chA);
                pa0 = v;
            }
            if (tid < 8) {
                int s = s0 - 1 + taA1;
                uint4 v = make_uint4(0u, 0u, 0u, 0u);
                if (s >= 0 && s < S_) v = *(const uint4*)(const void*)(inb + (size_t)s * D_ + c0 + chA);
                pa1 = v;
            }
            #pragma unroll
            for (int rr = 0; rr < 3; ++rr)
                pb[rr] = *(const uint4*)(const void*)(wtp + ((size_t)kb[rr] * 256 + (o0 + obv[rr])) * 256 + c0 + hB[rr] * 8);
        };
        pref(0);
        for (int c0 = 0; c0 < D_; c0 += 32) {
            *(uint4*)(void*)&Asb[taA0 * 40 + chA] = pa0;
            if (tid < 8) *(uint4*)(void*)&Asb[taA1 * 40 + chA] = pa1;
            #pragma unroll
            for (int rr = 0; rr < 3; ++rr)
                *(uint4*)(void*)&Bsb[dstB[rr]] = pb[rr];
            __syncthreads();
            if (c0 + 32 < D_) pref(c0 + 32);
            #pragma unroll
            for (int k = 0; k < 3; ++k) {
                short8x af = *(short8x*)(void*)&Asb[(wm + lm + k) * 40 + lk8];
                #pragma unroll
                for (int nt = 0; nt < 4; ++nt) {
                    short8x bf = *(short8x*)(void*)&Bsb[(k * 4 + nt) * 512 + hk * 128 + lm * 8];
                    acc[nt] = __builtin_amdgcn_mfma_f32_16x16x32_bf16(af, bf, acc[nt], 0, 0, 0);
                }
            }
            __syncthreads();
        }
        // epilogue: C/D layout col=lane&15, row=(lane>>4)*4+reg
        const int q4 = hk << 2;
        #pragma unroll
        for (int nt = 0; nt < 4; ++nt) {
            int o = o0 + (nt << 4) + lm;
            float bv = bias[o];
            #pragma unroll
            for (int rg = 0; rg < 4; ++rg) {
                int s = s0 + wm + q4 + rg;
                float v = fmaxf(acc[nt][rg] + bv, 0.f);
                size_t off = ((size_t)b * S_ + s) * D_ + o;
                if (cb.bfout) ((unsigned short*)cb.out[z1])[off] = f2bf(v);
                else          ((float*)cb.out[z1])[off] = v;
            }
        }
    }
}

// ============================================================
// K5: fused final linears + epilogues. 1 wave = 1 row.
// ============================================================
__global__ __launch_bounds__(256) void linfused_kernel(
    const float* __restrict__ h2dp, const float* __restrict__ h2pp, const float* __restrict__ h2ep,
    const float* __restrict__ dp_wl, const float* __restrict__ dp_bl,
    const float* __restrict__ pp_wl, const float* __restrict__ pp_bl,
    const float* __restrict__ ep_wl, const float* __restrict__ ep_bl,
    const float* __restrict__ nxn, const float* __restrict__ nx, const unsigned* __restrict__ red,
    float* __restrict__ o_logdur, float* __restrict__ o_dur, float* __restrict__ durf,
    float* __restrict__ o_pitch, float* __restrict__ o_energy)
{
    int row = blockIdx.x * 4 + (threadIdx.x >> 6);
    int lane = threadIdx.x & 63;
    float4 hd = ((const float4*)(h2dp + (size_t)row * F_))[lane];
    float4 wd = ((const float4*)dp_wl)[lane];
    float ad = hd.x * wd.x + hd.y * wd.y + hd.z * wd.z + hd.w * wd.w;

    float4 he = ((const float4*)(h2ep + (size_t)row * F_))[lane];
    float4 we = ((const float4*)ep_wl)[lane];
    float ae = he.x * we.x + he.y * we.y + he.z * we.z + he.w * we.w;

    float4 hp = ((const float4*)(h2pp + (size_t)row * F_))[lane];
    float hv[4] = { hp.x, hp.y, hp.z, hp.w };
    float a0 = 0.f, a1 = 0.f, a2 = 0.f;
    #pragma unroll
    for (int u = 0; u < 4; ++u) {
        int c = lane * 4 + u;
        a0 = fmaf(hv[u], pp_wl[c * 3 + 0], a0);
        a1 = fmaf(hv[u], pp_wl[c * 3 + 1], a1);
        a2 = fmaf(hv[u], pp_wl[c * 3 + 2], a2);
    }
    #pragma unroll
    for (int m = 32; m; m >>= 1) {
        ad += __shfl_xor(ad, m);
        ae += __shfl_xor(ae, m);
        a0 += __shfl_xor(a0, m); a1 += __shfl_xor(a1, m); a2 += __shfl_xor(a2, m);
    }
    if (lane == 0) {
        float base = ad + dp_bl[0];
        float es = 0.8f + 0.4f * (nxn[row] / __uint_as_float(red[0]));
        int s = row & (S_ - 1);
        float ps = 1.0f + 0.1f * ((float)s * (1.f / (float)S_));
        float ld = base * es * ps;
        float d = expf(ld);
        o_logdur[row] = ld;
        o_dur[row] = d;
        durf[row] = d;
        float p0 = a0 + pp_bl[0], p1 = a1 + pp_bl[1], p2 = a2 + pp_bl[2];
        float mn = __uint_as_float(red[1]), mx = __uint_as_float(red[2]);
        float en = (nx[row] - mn) / (mx - mn + 1e-8f);
        float f0s = 100.f + 400.f * en;
        float f0b = expf(p0) * f0s * (1.f / 220.f);
        o_pitch[(size_t)row * 3 + 0] = logf(f0b + 1e-8f);
        o_pitch[(size_t)row * 3 + 1] = p1;
        o_pitch[(size_t)row * 3 + 2] = p2;
        o_energy[row] = ae + ep_bl[0];
    }
}

// ============================================================
// K6: per-batch round->cumsum->clip, then RANGE-SCATTER idx + mask
// (replaces per-frame binary search). 1 block per batch.
// ============================================================
__global__ __launch_bounds__(1024) void regulate_kernel(
    const float* __restrict__ durf, int* __restrict__ idxbuf, float* __restrict__ mask)
{
    __shared__ int cum[S_];
    int b = blockIdx.x;
    int t = threadIdx.x;
    int d = (int)rintf(durf[b * S_ + t]);   // round-half-even, matches jnp.round
    cum[t] = d;
    __syncthreads();
    for (int off = 1; off < S_; off <<= 1) {
        int v = (t >= off) ? cum[t - off] : 0;
        __syncthreads();
        cum[t] += v;
        __syncthreads();
    }
    cum[t] = min(cum[t], T_);
    __syncthreads();
    int total = cum[S_ - 1];
    int lo = (t == 0) ? 0 : cum[t - 1];
    int hi = cum[t];
    int* idxb = idxbuf + b * T_;
    for (int f = lo; f < hi; ++f) idxb[f] = t;     // phoneme t owns frames [lo,hi)
    float* mb = mask + (size_t)b * T_;
    for (int f = t; f < T_; f += S_) {
        bool masked = (f >= total);
        mb[f] = masked ? 1.f : 0.f;
        if (masked) idxb[f] = -1;
    }
}

// ============================================================
// K7: expanded gather. 1 wave = 1 (b,t) row, float4/lane
// ============================================================
__global__ __launch_bounds__(256) void expand_kernel(
    const float* __restrict__ xp, const int* __restrict__ idxbuf, float* __restrict__ expd)
{
    int row = blockIdx.x * 4 + (threadIdx.x >> 6);
    int lane = threadIdx.x & 63;
    int id = idxbuf[row];
    int b = row >> 13;
    float4 v = make_float4(0.f, 0.f, 0.f, 0.f);
    if (id >= 0)
        v = ((const float4*)(xp + ((size_t)(b * S_ + id)) * D_))[lane];
    ((float4*)(expd + (size_t)row * D_))[lane] = v;
}

// ============================================================
extern "C" void kernel_launch(void* const* d_in, const int* in_sizes, int n_in,
                              void* d_out, int out_size, void* d_ws, size_t ws_size,
                              hipStream_t stream) {
    const float* x     = (const float*)d_in[0];
    const float* note  = (const float*)d_in[2];
    const float* ln_g  = (const float*)d_in[3];
    const float* ln_b  = (const float*)d_in[4];
    const float* dp_w1 = (const float*)d_in[5];
    const float* dp_b1 = (const float*)d_in[6];
    const float* dp_w2 = (const float*)d_in[7];
    const float* dp_b2 = (const float*)d_in[8];
    const float* dp_wl = (const float*)d_in[9];
    const float* dp_bl = (const float*)d_in[10];
    const float* pp_w1 = (const float*)d_in[11];
    const float* pp_b1 = (const float*)d_in[12];
    const float* pp_w2 = (const float*)d_in[13];
    const float* pp_b2 = (const float*)d_in[14];
    const float* pp_wl = (const float*)d_in[15];
    const float* pp_bl = (const float*)d_in[16];
    const float* ep_w1 = (const float*)d_in[17];
    const float* ep_b1 = (const float*)d_in[18];
    const float* ep_w2 = (const float*)d_in[19];
    const float* ep_b2 = (const float*)d_in[20];
    const float* ep_wl = (const float*)d_in[21];
    const float* ep_bl = (const float*)d_in[22];
    const float* np_w  = (const float*)d_in[23];
    const float* np_b  = (const float*)d_in[24];

    // d_out: logdur | dur | pitch | energy | expanded | melmask
    float* o_logdur = (float*)d_out;
    float* o_dur    = o_logdur + ROWS;
    float* o_pitch  = o_dur + ROWS;
    float* o_energy = o_pitch + ROWS * 3;
    float* o_exp    = o_energy + ROWS;
    float* o_mask   = o_exp + (size_t)B_ * T_ * D_;

    // intermediates inside the expanded region (rewritten last by expand)
    const size_t CH = (size_t)ROWS * D_;      // 4,194,304 floats
    float* xn    = o_exp;
    float* h1_dp = o_exp + 1 * CH;
    float* h2_dp = o_exp + 2 * CH;
    float* h2_pp = o_exp + 3 * CH;
    float* h2_ep = o_exp + 4 * CH;
    unsigned short* h1_ppb = (unsigned short*)(o_exp + 5 * CH);            // CH bf16
    unsigned short* h1_epb = (unsigned short*)(o_exp + 5 * CH + CH / 2);   // CH bf16
    unsigned short* xp_bf  = (unsigned short*)(o_exp + 6 * CH);            // CH bf16
    unsigned short* wt     = (unsigned short*)(o_exp + 6 * CH + CH / 2);   // 786432 bf16
    unsigned short* wt_pp1 = wt;
    unsigned short* wt_ep1 = wt + 196608;
    unsigned short* wt_pp2 = wt + 2 * 196608;
    unsigned short* wt_ep2 = wt + 3 * 196608;

    // d_ws: xprime | norm_xn | norm_x | red | durf | idx
    float* ws_f    = (float*)d_ws;
    float* xprime  = ws_f;
    float* norm_xn = ws_f + CH;
    float* norm_x  = norm_xn + ROWS;
    unsigned* red  = (unsigned*)(norm_x + ROWS);
    float* durf    = (float*)(red + 4);
    int*   idxbuf  = (int*)(durf + ROWS);

    noteproj_kernel<<<dim3(256, 4, 2), 256, 0, stream>>>(
        x, note, np_w, np_b, xprime, red, pp_w1, ep_w1, pp_w2, ep_w2, wt);
    rowstats_kernel<<<ROWS / 4, 256, 0, stream>>>(xprime, ln_g, ln_b, xn, norm_xn, norm_x, xp_bf);
    reduce_fast_kernel<<<32, 256, 0, stream>>>(norm_xn, norm_x, red);

    dim3 cgrid(256, 4, 3);
    ConvMix s1;
    s1.in0 = xn; s1.w0 = dp_w1; s1.b0 = dp_b1; s1.out0 = h1_dp;
    s1.inb[0] = xp_bf;  s1.wt[0] = wt_pp1; s1.bias[0] = pp_b1; s1.out[0] = (void*)h1_ppb;
    s1.inb[1] = xp_bf;  s1.wt[1] = wt_ep1; s1.bias[1] = ep_b1; s1.out[1] = (void*)h1_epb;
    s1.bfout = 1;
    convmix_kernel<<<cgrid, 256, 0, stream>>>(s1);

    ConvMix s2;
    s2.in0 = h1_dp; s2.w0 = dp_w2; s2.b0 = dp_b2; s2.out0 = h2_dp;
    s2.inb[0] = h1_ppb; s2.wt[0] = wt_pp2; s2.bias[0] = pp_b2; s2.out[0] = (void*)h2_pp;
    s2.inb[1] = h1_epb; s2.wt[1] = wt_ep2; s2.bias[1] = ep_b2; s2.out[1] = (void*)h2_ep;
    s2.bfout = 0;
    convmix_kernel<<<cgrid, 256, 0, stream>>>(s2);

    linfused_kernel<<<ROWS / 4, 256, 0, stream>>>(h2_dp, h2_pp, h2_ep,
        dp_wl, dp_bl, pp_wl, pp_bl, ep_wl, ep_bl,
        norm_xn, norm_x, red, o_logdur, o_dur, durf, o_pitch, o_energy);

    regulate_kernel<<<B_, 1024, 0, stream>>>(durf, idxbuf, o_mask);
    expand_kernel<<<(B_ * T_) / 4, 256, 0, stream>>>(xprime, idxbuf, o_exp);
}

// Round 5
// 505.523 us; speedup vs baseline: 1.1673x; 1.1673x over previous
//
#include <hip/hip_runtime.h>
#include <math.h>

#define B_ 16
#define S_ 1024
#define D_ 256
#define F_ 256
#define T_ 8192
#define ROWS (B_ * S_)  // 16384

typedef __attribute__((ext_vector_type(8))) short short8x;
typedef __attribute__((ext_vector_type(4))) float f32x4;

static __device__ __forceinline__ unsigned short f2bf(float f) {
    unsigned u = __float_as_uint(f);
    unsigned r = (u + 0x7FFFu + ((u >> 16) & 1u)) >> 16;  // round-to-nearest-even
    return (unsigned short)r;
}

// ============================================================
// K1: z=0: x' = x + note_pitch @ np_w + np_b  (BM=64 BN=64, 4x4/thread)
//     z=1: bf16 weight prep wt[t][k][o][c] (t in {pp1,ep1,pp2,ep2}) + red init
// grid (256, 4, 2)
// ============================================================
__global__ __launch_bounds__(256) void noteproj_kernel(
    const float* __restrict__ x, const float* __restrict__ note,
    const float* __restrict__ w, const float* __restrict__ bias,
    float* __restrict__ xp, unsigned* __restrict__ red,
    const float* __restrict__ pw1, const float* __restrict__ ew1,
    const float* __restrict__ pw2, const float* __restrict__ ew2,
    unsigned short* __restrict__ wt)
{
    if (blockIdx.z == 1) {
        int flat = blockIdx.y * 256 + blockIdx.x;           // 0..1023
        if (flat == 0 && threadIdx.x == 0) {
            red[0] = 0u;            // max ||xn||
            red[1] = 0x7F7FFFFFu;   // min ||x'||
            red[2] = 0u;            // max ||x'||
        }
        int idx = flat * 256 + threadIdx.x;                 // 0..262143
        int t = idx >> 16;
        int rem = idx & 65535;
        int o = rem >> 8, c = rem & 255;
        const float* src = (t == 0) ? pw1 : (t == 1) ? ew1 : (t == 2) ? pw2 : ew2;
        const float* p = src + ((size_t)o * 256 + c) * 3;
        unsigned short* dst = wt + (size_t)t * 196608;
        #pragma unroll
        for (int k = 0; k < 3; ++k)
            dst[((size_t)k * 256 + o) * 256 + c] = f2bf(p[k]);
        return;
    }
    __shared__ float As[16][66];
    __shared__ float Bs[16][68];
    const int tid = threadIdx.x;
    const int m0 = blockIdx.x << 6;
    const int o0 = blockIdx.y << 6;
    const int tc = tid & 15, tr = tid >> 4;
    const int r = tr << 2, oc = tc << 2;
    const int tA = tid >> 2, cg = (tid & 3) << 2;
    const int cB = tid >> 4, oB = (tid & 15) << 2;
    float acc[4][4] = {};

    for (int c0 = 0; c0 < D_; c0 += 16) {
        float4 av = *(const float4*)(note + (size_t)(m0 + tA) * D_ + c0 + cg);
        As[cg + 0][tA] = av.x; As[cg + 1][tA] = av.y;
        As[cg + 2][tA] = av.z; As[cg + 3][tA] = av.w;
        *(float4*)&Bs[cB][oB] = *(const float4*)(w + (size_t)(c0 + cB) * D_ + o0 + oB);
        __syncthreads();
        #pragma unroll
        for (int c = 0; c < 16; ++c) {
            float a[4], bv[4];
            #pragma unroll
            for (int m = 0; m < 4; ++m) a[m] = As[c][r + m];
            #pragma unroll
            for (int j = 0; j < 4; ++j) bv[j] = Bs[c][oc + j];
            #pragma unroll
            for (int i = 0; i < 4; ++i)
                #pragma unroll
                for (int j = 0; j < 4; ++j)
                    acc[i][j] = fmaf(a[i], bv[j], acc[i][j]);
        }
        __syncthreads();
    }
    #pragma unroll
    for (int i = 0; i < 4; ++i) {
        size_t row = (size_t)(m0 + r + i);
        const float* xr = x + row * D_ + o0 + oc;
        float4 v;
        v.x = acc[i][0] + bias[o0 + oc + 0] + xr[0];
        v.y = acc[i][1] + bias[o0 + oc + 1] + xr[1];
        v.z = acc[i][2] + bias[o0 + oc + 2] + xr[2];
        v.w = acc[i][3] + bias[o0 + oc + 3] + xr[3];
        *(float4*)(xp + row * D_ + o0 + oc) = v;
    }
}

// ============================================================
// K2: layernorm + norms + bf16 copy of x'. 1 wave = 1 row.
// ============================================================
__global__ __launch_bounds__(256) void rowstats_kernel(
    const float* __restrict__ xp, const float* __restrict__ g, const float* __restrict__ bb,
    float* __restrict__ xn, float* __restrict__ nxn, float* __restrict__ nx,
    unsigned short* __restrict__ xpb)
{
    int row = blockIdx.x * 4 + (threadIdx.x >> 6);
    int lane = threadIdx.x & 63;
    float4 v = ((const float4*)(xp + (size_t)row * D_))[lane];
    ushort4 bv4;
    bv4.x = f2bf(v.x); bv4.y = f2bf(v.y); bv4.z = f2bf(v.z); bv4.w = f2bf(v.w);
    ((ushort4*)xpb)[(size_t)row * 64 + lane] = bv4;

    float s = v.x + v.y + v.z + v.w;
    float sq = v.x * v.x + v.y * v.y + v.z * v.z + v.w * v.w;
    #pragma unroll
    for (int m = 32; m; m >>= 1) { s += __shfl_xor(s, m); sq += __shfl_xor(sq, m); }
    float mean = s * (1.f / 256.f);
    float var = sq * (1.f / 256.f) - mean * mean;
    float rs = rsqrtf(var + 1e-5f);
    float4 gv = ((const float4*)g)[lane];
    float4 bv = ((const float4*)bb)[lane];
    float4 o;
    o.x = gv.x * (v.x - mean) * rs + bv.x;
    o.y = gv.y * (v.y - mean) * rs + bv.y;
    o.z = gv.z * (v.z - mean) * rs + bv.z;
    o.w = gv.w * (v.w - mean) * rs + bv.w;
    ((float4*)(xn + (size_t)row * D_))[lane] = o;
    float q = o.x * o.x + o.y * o.y + o.z * o.z + o.w * o.w;
    #pragma unroll
    for (int m = 32; m; m >>= 1) q += __shfl_xor(q, m);
    if (lane == 0) { nxn[row] = sqrtf(q); nx[row] = sqrtf(sq); }
}

// ============================================================
// K3: global reduce via uint-monotonic atomics (positive floats)
// ============================================================
__global__ __launch_bounds__(256) void reduce_fast_kernel(
    const float* __restrict__ nxn, const float* __restrict__ nx, unsigned* __restrict__ red)
{
    int tid = threadIdx.x;
    int lane = tid & 63, wave = tid >> 6;
    float mxn = 0.f, mnx = 3.0e38f, mxx = 0.f;
    for (int i = blockIdx.x * 256 + tid; i < ROWS; i += 32 * 256) {
        mxn = fmaxf(mxn, nxn[i]);
        float v = nx[i];
        mnx = fminf(mnx, v);
        mxx = fmaxf(mxx, v);
    }
    #pragma unroll
    for (int m = 32; m; m >>= 1) {
        mxn = fmaxf(mxn, __shfl_xor(mxn, m));
        mnx = fminf(mnx, __shfl_xor(mnx, m));
        mxx = fmaxf(mxx, __shfl_xor(mxx, m));
    }
    __shared__ float a0[4], a1[4], a2[4];
    if (lane == 0) { a0[wave] = mxn; a1[wave] = mnx; a2[wave] = mxx; }
    __syncthreads();
    if (tid == 0) {
        #pragma unroll
        for (int w2 = 1; w2 < 4; ++w2) {
            mxn = fmaxf(mxn, a0[w2]); mnx = fminf(mnx, a1[w2]); mxx = fmaxf(mxx, a2[w2]);
        }
        atomicMax(&red[0], __float_as_uint(mxn));
        atomicMin(&red[1], __float_as_uint(mnx));
        atomicMax(&red[2], __float_as_uint(mxx));
    }
}

// ============================================================
// K4: mixed conv stage, BM=64 everywhere.
//   z=0: dp fp32 (1024 blocks, 4x4/thread, reg prefetch)
//   z=1,2: pp/ep bf16 MFMA (2048 light blocks, swizzled B tile)
// grid (256, 4, 3)
// __launch_bounds__(256,4): vgpr cap 128 -- R4's (256,6) forced vgpr<=64,
// spilled to scratch (VGPR 40, WRITE_SIZE 48->248 MB, 590 us regression).
// ============================================================
struct ConvMix {
    const float* in0; const float* w0; const float* b0; float* out0;   // dp fp32
    const unsigned short* inb[2];     // bf16 inputs [B*S][256]
    const unsigned short* wt[2];      // bf16 weights [3][256][256]
    const float* bias[2];
    void* out[2];
    int bfout;                        // 1: write bf16, 0: write fp32
};

__global__ __launch_bounds__(256, 4) void convmix_kernel(ConvMix cb)
{
    __shared__ __align__(16) char smem[17664];
    const int tid = threadIdx.x;
    const int z = blockIdx.z;
    const int b = blockIdx.x >> 4;
    const int s0 = (blockIdx.x & 15) << 6;
    const int o0 = blockIdx.y << 6;

    if (z == 0) {
        // ---------------- fp32 dp path, BM=64 ----------------
        float* AsF = (float*)smem;            // [16][68]  (t dim 0..65)
        float* BsF = (float*)(smem + 4352);   // [3][16][68]
        const int tc = tid & 15, tr = tid >> 4;
        const int r = tr << 2, oc = tc << 2;
        const int oB = tid >> 2;
        const int qB = (tid & 3) * 12;
        const int rowA0 = tid >> 2, cgA0 = (tid & 3) << 2;   // slot tid
        const int rowA1 = 64 + (tid >> 2);                   // slot tid+256 (tid<8)
        const float* inb = cb.in0 + (size_t)b * S_ * D_;
        float acc[4][4] = {};
        float4 pa0, pa1; float pb[12];

        auto pref = [&](int c0) {
            {
                int s = s0 - 1 + rowA0;
                float4 v = make_float4(0.f, 0.f, 0.f, 0.f);
                if (s >= 0 && s < S_) v = *(const float4*)(inb + (size_t)s * D_ + c0 + cgA0);
                pa0 = v;
            }
            if (tid < 8) {
                int s = s0 - 1 + rowA1;
                float4 v = make_float4(0.f, 0.f, 0.f, 0.f);
                if (s >= 0 && s < S_) v = *(const float4*)(inb + (size_t)s * D_ + c0 + cgA0);
                pa1 = v;
            }
            const float* wp = cb.w0 + ((size_t)(o0 + oB) * D_ + c0) * 3 + qB;
            #pragma unroll
            for (int j = 0; j < 12; ++j) pb[j] = wp[j];
        };
        pref(0);
        for (int c0 = 0; c0 < D_; c0 += 16) {
            AsF[(cgA0 + 0) * 68 + rowA0] = pa0.x;
            AsF[(cgA0 + 1) * 68 + rowA0] = pa0.y;
            AsF[(cgA0 + 2) * 68 + rowA0] = pa0.z;
            AsF[(cgA0 + 3) * 68 + rowA0] = pa0.w;
            if (tid < 8) {
                AsF[(cgA0 + 0) * 68 + rowA1] = pa1.x;
                AsF[(cgA0 + 1) * 68 + rowA1] = pa1.y;
                AsF[(cgA0 + 2) * 68 + rowA1] = pa1.z;
                AsF[(cgA0 + 3) * 68 + rowA1] = pa1.w;
            }
            #pragma unroll
            for (int j = 0; j < 12; ++j) {
                int m = qB + j;
                BsF[((m % 3) * 16 + (m / 3)) * 68 + oB] = pb[j];
            }
            __syncthreads();
            if (c0 + 16 < D_) pref(c0 + 16);
            #pragma unroll
            for (int c = 0; c < 16; ++c) {
                float a[6];
                #pragma unroll
                for (int m = 0; m < 6; ++m) a[m] = AsF[c * 68 + r + m];
                #pragma unroll
                for (int k = 0; k < 3; ++k) {
                    float4 bv = *(const float4*)&BsF[(k * 16 + c) * 68 + oc];
                    #pragma unroll
                    for (int i = 0; i < 4; ++i) {
                        float av = a[i + k];
                        acc[i][0] = fmaf(av, bv.x, acc[i][0]);
                        acc[i][1] = fmaf(av, bv.y, acc[i][1]);
                        acc[i][2] = fmaf(av, bv.z, acc[i][2]);
                        acc[i][3] = fmaf(av, bv.w, acc[i][3]);
                    }
                }
            }
            __syncthreads();
        }
        float bj0 = cb.b0[o0 + oc + 0], bj1 = cb.b0[o0 + oc + 1];
        float bj2 = cb.b0[o0 + oc + 2], bj3 = cb.b0[o0 + oc + 3];
        float* outb = cb.out0 + (size_t)b * S_ * D_;
        #pragma unroll
        for (int i = 0; i < 4; ++i) {
            int s = s0 + r + i;
            float4 v;
            v.x = fmaxf(acc[i][0] + bj0, 0.f);
            v.y = fmaxf(acc[i][1] + bj1, 0.f);
            v.z = fmaxf(acc[i][2] + bj2, 0.f);
            v.w = fmaxf(acc[i][3] + bj3, 0.f);
            *(float4*)(outb + (size_t)s * D_ + o0 + oc) = v;
        }
    } else {
        // ---------------- bf16 MFMA path (pp/ep), BM=64 ----------------
        const int z1 = z - 1;
        unsigned short* Asb = (unsigned short*)smem;            // [66][40]
        unsigned short* Bsb = (unsigned short*)(smem + 5280);   // [3][4][4][16][8] = 6144 shorts
        const unsigned short* inb = cb.inb[z1] + (size_t)b * S_ * D_;
        const unsigned short* wtp = cb.wt[z1];
        const float* bias = cb.bias[z1];
        const int wave = tid >> 6, lane = tid & 63;
        const int wm = wave << 4;              // 16 rows per wave
        const int lm = lane & 15, hk = lane >> 4, lk8 = hk << 3;
        f32x4 acc[4] = {};

        // A staging: 66 rows x 4 chunks = 264 slots
        const int taA0 = tid >> 2, chA = (tid & 3) << 3;      // slot tid
        const int taA1 = 64 + (tid >> 2);                     // slot tid+256 (tid<8)
        // B staging: 768 slots, swizzled dest [k][nt][h][lm]
        int kb[3], obv[3], hB[3], dstB[3];
        #pragma unroll
        for (int rr = 0; rr < 3; ++rr) {
            int slotB = tid + (rr << 8);
            kb[rr] = slotB >> 8;
            int rem = slotB & 255;
            obv[rr] = rem >> 2;
            hB[rr] = rem & 3;
            dstB[rr] = (kb[rr] * 4 + (obv[rr] >> 4)) * 512 + hB[rr] * 128 + (obv[rr] & 15) * 8;
        }
        uint4 pa0, pa1, pb[3];
        auto pref = [&](int c0) {
            {
                int s = s0 - 1 + taA0;
                uint4 v = make_uint4(0u, 0u, 0u, 0u);
                if (s >= 0 && s < S_) v = *(const uint4*)(const void*)(inb + (size_t)s * D_ + c0 + chA);
                pa0 = v;
            }
            if (tid < 8) {
                int s = s0 - 1 + taA1;
                uint4 v = make_uint4(0u, 0u, 0u, 0u);
                if (s >= 0 && s < S_) v = *(const uint4*)(const void*)(inb + (size_t)s * D_ + c0 + chA);
                pa1 = v;
            }
            #pragma unroll
            for (int rr = 0; rr < 3; ++rr)
                pb[rr] = *(const uint4*)(const void*)(wtp + ((size_t)kb[rr] * 256 + (o0 + obv[rr])) * 256 + c0 + hB[rr] * 8);
        };
        pref(0);
        for (int c0 = 0; c0 < D_; c0 += 32) {
            *(uint4*)(void*)&Asb[taA0 * 40 + chA] = pa0;
            if (tid < 8) *(uint4*)(void*)&Asb[taA1 * 40 + chA] = pa1;
            #pragma unroll
            for (int rr = 0; rr < 3; ++rr)
                *(uint4*)(void*)&Bsb[dstB[rr]] = pb[rr];
            __syncthreads();
            if (c0 + 32 < D_) pref(c0 + 32);
            #pragma unroll
            for (int k = 0; k < 3; ++k) {
                short8x af = *(short8x*)(void*)&Asb[(wm + lm + k) * 40 + lk8];
                #pragma unroll
                for (int nt = 0; nt < 4; ++nt) {
                    short8x bf = *(short8x*)(void*)&Bsb[(k * 4 + nt) * 512 + hk * 128 + lm * 8];
                    acc[nt] = __builtin_amdgcn_mfma_f32_16x16x32_bf16(af, bf, acc[nt], 0, 0, 0);
                }
            }
            __syncthreads();
        }
        // epilogue: C/D layout col=lane&15, row=(lane>>4)*4+reg
        const int q4 = hk << 2;
        #pragma unroll
        for (int nt = 0; nt < 4; ++nt) {
            int o = o0 + (nt << 4) + lm;
            float bv = bias[o];
            #pragma unroll
            for (int rg = 0; rg < 4; ++rg) {
                int s = s0 + wm + q4 + rg;
                float v = fmaxf(acc[nt][rg] + bv, 0.f);
                size_t off = ((size_t)b * S_ + s) * D_ + o;
                if (cb.bfout) ((unsigned short*)cb.out[z1])[off] = f2bf(v);
                else          ((float*)cb.out[z1])[off] = v;
            }
        }
    }
}

// ============================================================
// K5: fused final linears + epilogues. 1 wave = 1 row.
// ============================================================
__global__ __launch_bounds__(256) void linfused_kernel(
    const float* __restrict__ h2dp, const float* __restrict__ h2pp, const float* __restrict__ h2ep,
    const float* __restrict__ dp_wl, const float* __restrict__ dp_bl,
    const float* __restrict__ pp_wl, const float* __restrict__ pp_bl,
    const float* __restrict__ ep_wl, const float* __restrict__ ep_bl,
    const float* __restrict__ nxn, const float* __restrict__ nx, const unsigned* __restrict__ red,
    float* __restrict__ o_logdur, float* __restrict__ o_dur, float* __restrict__ durf,
    float* __restrict__ o_pitch, float* __restrict__ o_energy)
{
    int row = blockIdx.x * 4 + (threadIdx.x >> 6);
    int lane = threadIdx.x & 63;
    float4 hd = ((const float4*)(h2dp + (size_t)row * F_))[lane];
    float4 wd = ((const float4*)dp_wl)[lane];
    float ad = hd.x * wd.x + hd.y * wd.y + hd.z * wd.z + hd.w * wd.w;

    float4 he = ((const float4*)(h2ep + (size_t)row * F_))[lane];
    float4 we = ((const float4*)ep_wl)[lane];
    float ae = he.x * we.x + he.y * we.y + he.z * we.z + he.w * we.w;

    float4 hp = ((const float4*)(h2pp + (size_t)row * F_))[lane];
    float hv[4] = { hp.x, hp.y, hp.z, hp.w };
    float a0 = 0.f, a1 = 0.f, a2 = 0.f;
    #pragma unroll
    for (int u = 0; u < 4; ++u) {
        int c = lane * 4 + u;
        a0 = fmaf(hv[u], pp_wl[c * 3 + 0], a0);
        a1 = fmaf(hv[u], pp_wl[c * 3 + 1], a1);
        a2 = fmaf(hv[u], pp_wl[c * 3 + 2], a2);
    }
    #pragma unroll
    for (int m = 32; m; m >>= 1) {
        ad += __shfl_xor(ad, m);
        ae += __shfl_xor(ae, m);
        a0 += __shfl_xor(a0, m); a1 += __shfl_xor(a1, m); a2 += __shfl_xor(a2, m);
    }
    if (lane == 0) {
        float base = ad + dp_bl[0];
        float es = 0.8f + 0.4f * (nxn[row] / __uint_as_float(red[0]));
        int s = row & (S_ - 1);
        float ps = 1.0f + 0.1f * ((float)s * (1.f / (float)S_));
        float ld = base * es * ps;
        float d = expf(ld);
        o_logdur[row] = ld;
        o_dur[row] = d;
        durf[row] = d;
        float p0 = a0 + pp_bl[0], p1 = a1 + pp_bl[1], p2 = a2 + pp_bl[2];
        float mn = __uint_as_float(red[1]), mx = __uint_as_float(red[2]);
        float en = (nx[row] - mn) / (mx - mn + 1e-8f);
        float f0s = 100.f + 400.f * en;
        float f0b = expf(p0) * f0s * (1.f / 220.f);
        o_pitch[(size_t)row * 3 + 0] = logf(f0b + 1e-8f);
        o_pitch[(size_t)row * 3 + 1] = p1;
        o_pitch[(size_t)row * 3 + 2] = p2;
        o_energy[row] = ae + ep_bl[0];
    }
}

// ============================================================
// K6: per-batch round->cumsum->clip, then RANGE-SCATTER idx + mask
// ============================================================
__global__ __launch_bounds__(1024) void regulate_kernel(
    const float* __restrict__ durf, int* __restrict__ idxbuf, float* __restrict__ mask)
{
    __shared__ int cum[S_];
    int b = blockIdx.x;
    int t = threadIdx.x;
    int d = (int)rintf(durf[b * S_ + t]);   // round-half-even, matches jnp.round
    cum[t] = d;
    __syncthreads();
    for (int off = 1; off < S_; off <<= 1) {
        int v = (t >= off) ? cum[t - off] : 0;
        __syncthreads();
        cum[t] += v;
        __syncthreads();
    }
    cum[t] = min(cum[t], T_);
    __syncthreads();
    int total = cum[S_ - 1];
    int lo = (t == 0) ? 0 : cum[t - 1];
    int hi = cum[t];
    int* idxb = idxbuf + b * T_;
    for (int f = lo; f < hi; ++f) idxb[f] = t;     // phoneme t owns frames [lo,hi)
    float* mb = mask + (size_t)b * T_;
    for (int f = t; f < T_; f += S_) {
        bool masked = (f >= total);
        mb[f] = masked ? 1.f : 0.f;
        if (masked) idxb[f] = -1;
    }
}

// ============================================================
// K7: expanded gather. 1 wave = 1 (b,t) row, float4/lane
// ============================================================
__global__ __launch_bounds__(256) void expand_kernel(
    const float* __restrict__ xp, const int* __restrict__ idxbuf, float* __restrict__ expd)
{
    int row = blockIdx.x * 4 + (threadIdx.x >> 6);
    int lane = threadIdx.x & 63;
    int id = idxbuf[row];
    int b = row >> 13;
    float4 v = make_float4(0.f, 0.f, 0.f, 0.f);
    if (id >= 0)
        v = ((const float4*)(xp + ((size_t)(b * S_ + id)) * D_))[lane];
    ((float4*)(expd + (size_t)row * D_))[lane] = v;
}

// ============================================================
extern "C" void kernel_launch(void* const* d_in, const int* in_sizes, int n_in,
                              void* d_out, int out_size, void* d_ws, size_t ws_size,
                              hipStream_t stream) {
    const float* x     = (const float*)d_in[0];
    const float* note  = (const float*)d_in[2];
    const float* ln_g  = (const float*)d_in[3];
    const float* ln_b  = (const float*)d_in[4];
    const float* dp_w1 = (const float*)d_in[5];
    const float* dp_b1 = (const float*)d_in[6];
    const float* dp_w2 = (const float*)d_in[7];
    const float* dp_b2 = (const float*)d_in[8];
    const float* dp_wl = (const float*)d_in[9];
    const float* dp_bl = (const float*)d_in[10];
    const float* pp_w1 = (const float*)d_in[11];
    const float* pp_b1 = (const float*)d_in[12];
    const float* pp_w2 = (const float*)d_in[13];
    const float* pp_b2 = (const float*)d_in[14];
    const float* pp_wl = (const float*)d_in[15];
    const float* pp_bl = (const float*)d_in[16];
    const float* ep_w1 = (const float*)d_in[17];
    const float* ep_b1 = (const float*)d_in[18];
    const float* ep_w2 = (const float*)d_in[19];
    const float* ep_b2 = (const float*)d_in[20];
    const float* ep_wl = (const float*)d_in[21];
    const float* ep_bl = (const float*)d_in[22];
    const float* np_w  = (const float*)d_in[23];
    const float* np_b  = (const float*)d_in[24];

    // d_out: logdur | dur | pitch | energy | expanded | melmask
    float* o_logdur = (float*)d_out;
    float* o_dur    = o_logdur + ROWS;
    float* o_pitch  = o_dur + ROWS;
    float* o_energy = o_pitch + ROWS * 3;
    float* o_exp    = o_energy + ROWS;
    float* o_mask   = o_exp + (size_t)B_ * T_ * D_;

    // intermediates inside the expanded region (rewritten last by expand)
    const size_t CH = (size_t)ROWS * D_;      // 4,194,304 floats
    float* xn    = o_exp;
    float* h1_dp = o_exp + 1 * CH;
    float* h2_dp = o_exp + 2 * CH;
    float* h2_pp = o_exp + 3 * CH;
    float* h2_ep = o_exp + 4 * CH;
    unsigned short* h1_ppb = (unsigned short*)(o_exp + 5 * CH);            // CH bf16
    unsigned short* h1_epb = (unsigned short*)(o_exp + 5 * CH + CH / 2);   // CH bf16
    unsigned short* xp_bf  = (unsigned short*)(o_exp + 6 * CH);            // CH bf16
    unsigned short* wt     = (unsigned short*)(o_exp + 6 * CH + CH / 2);   // 786432 bf16
    unsigned short* wt_pp1 = wt;
    unsigned short* wt_ep1 = wt + 196608;
    unsigned short* wt_pp2 = wt + 2 * 196608;
    unsigned short* wt_ep2 = wt + 3 * 196608;

    // d_ws: xprime | norm_xn | norm_x | red | durf | idx
    float* ws_f    = (float*)d_ws;
    float* xprime  = ws_f;
    float* norm_xn = ws_f + CH;
    float* norm_x  = norm_xn + ROWS;
    unsigned* red  = (unsigned*)(norm_x + ROWS);
    float* durf    = (float*)(red + 4);
    int*   idxbuf  = (int*)(durf + ROWS);

    noteproj_kernel<<<dim3(256, 4, 2), 256, 0, stream>>>(
        x, note, np_w, np_b, xprime, red, pp_w1, ep_w1, pp_w2, ep_w2, wt);
    rowstats_kernel<<<ROWS / 4, 256, 0, stream>>>(xprime, ln_g, ln_b, xn, norm_xn, norm_x, xp_bf);
    reduce_fast_kernel<<<32, 256, 0, stream>>>(norm_xn, norm_x, red);

    dim3 cgrid(256, 4, 3);
    ConvMix s1;
    s1.in0 = xn; s1.w0 = dp_w1; s1.b0 = dp_b1; s1.out0 = h1_dp;
    s1.inb[0] = xp_bf;  s1.wt[0] = wt_pp1; s1.bias[0] = pp_b1; s1.out[0] = (void*)h1_ppb;
    s1.inb[1] = xp_bf;  s1.wt[1] = wt_ep1; s1.bias[1] = ep_b1; s1.out[1] = (void*)h1_epb;
    s1.bfout = 1;
    convmix_kernel<<<cgrid, 256, 0, stream>>>(s1);

    ConvMix s2;
    s2.in0 = h1_dp; s2.w0 = dp_w2; s2.b0 = dp_b2; s2.out0 = h2_dp;
    s2.inb[0] = h1_ppb; s2.wt[0] = wt_pp2; s2.bias[0] = pp_b2; s2.out[0] = (void*)h2_pp;
    s2.inb[1] = h1_epb; s2.wt[1] = wt_ep2; s2.bias[1] = ep_b2; s2.out[1] = (void*)h2_ep;
    s2.bfout = 0;
    convmix_kernel<<<cgrid, 256, 0, stream>>>(s2);

    linfused_kernel<<<ROWS / 4, 256, 0, stream>>>(h2_dp, h2_pp, h2_ep,
        dp_wl, dp_bl, pp_wl, pp_bl, ep_wl, ep_bl,
        norm_xn, norm_x, red, o_logdur, o_dur, durf, o_pitch, o_energy);

    regulate_kernel<<<B_, 1024, 0, stream>>>(durf, idxbuf, o_mask);
    expand_kernel<<<(B_ * T_) / 4, 256, 0, stream>>>(xprime, idxbuf, o_exp);
}